// Round 1
// baseline (356.405 us; speedup 1.0000x reference)
//
#include <hip/hip_runtime.h>
#include <hip/hip_bf16.h>

// LinkPredictorGAT: out[e] = relu(concat(z[src[e]], z[dst[e]]) @ W1 + b1) @ W2 + b2
// R9 = R8 skeleton (256-thr, 3907 blocks, double-buffered swizzled LDS B, BK=128,
// global_load_lds width=16 staging) + two latency deltas:
//   1. T4 counted-vmcnt barriers: raw s_barrier + s_waitcnt vmcnt(16/12) instead of
//      __syncthreads(). Staging is pinned first (sched_barrier(0)) so FIFO vmcnt(16)
//      guarantees the 8 staging loads landed while gather prefetches stay in flight
//      across chunk boundaries (removes ~4 full vmcnt(0) drains/block).
//   2. A-gather lookahead 3->4 (A[4][4], consume ks, load ks+3): ~600cy cover vs
//      500-900cy L3/HBM gather latency. Reg-offset by splitting bfr into 2x4 so
//      arch VGPR stays ~112-120 (combined with 128 AGPR acc < 256 => 2 waves/SIMD).
// Occupancy is register+LDS pinned at 8 waves/CU; the lever here is per-wave ILP.

typedef __attribute__((ext_vector_type(4))) float floatx4;
typedef __attribute__((ext_vector_type(8))) short short8;

__device__ __forceinline__ unsigned short bf16rne(float x) {
    unsigned int u = __float_as_uint(x);
    u += 0x7fffu + ((u >> 16) & 1u);
    return (unsigned short)(u >> 16);
}

// async global->LDS, 16 B per lane; LDS dest = wave-uniform base + lane*16.
__device__ __forceinline__ void gl_lds16(const void* g, void* l) {
    __builtin_amdgcn_global_load_lds(
        (const __attribute__((address_space(1))) void*)(unsigned long long)g,
        (__attribute__((address_space(3))) void*)(unsigned)(unsigned long long)l,
        16, 0, 0);
}

// ---- convert z (fp32 -> bf16), float4 per thread ----
__global__ void cvt_z(const float* __restrict__ z, unsigned short* __restrict__ zb, int n4) {
    int i = blockIdx.x * blockDim.x + threadIdx.x;
    if (i < n4) {
        float4 f = ((const float4*)z)[i];
        ushort4 u;
        u.x = bf16rne(f.x); u.y = bf16rne(f.y);
        u.z = bf16rne(f.z); u.w = bf16rne(f.w);
        ((ushort4*)zb)[i] = u;
    }
}

// ---- convert W1 [512][128] fp32 -> BTc, linear image of the swizzled B layout ----
// L(s,n,g',j) = s*4096 + n*32 + g'*8 + j (shorts); s=k>>5, g=(k>>3)&3, j=k&7,
// g' = g ^ ((n>>1)&3). Reader: 0 bank conflicts (verified R6/R7).
__global__ void cvt_w1(const float* __restrict__ W1, unsigned short* __restrict__ BTc) {
    int t = blockIdx.x * blockDim.x + threadIdx.x;   // 0..65535
    int s = t >> 12, rem = t & 4095;
    int n = rem >> 5, rem2 = rem & 31;
    int gp = rem2 >> 3, j = rem2 & 7;
    int g = gp ^ ((n >> 1) & 3);
    int k = s * 32 + g * 8 + j;
    BTc[t] = bf16rne(W1[k * 128 + n]);
}

// ---- fused gather + GEMM(512x128) + bias + relu + GEMV(W2) ----
// 256 threads = 4 waves; wave tile 64 edges x 128 cols (mf=4, nf=8); 256 edges/block.
// LDS: 2 x 32 KB chunk buffers (BK=128 = 4 K32 slabs each) = 64 KB -> 2 blocks/CU.
template <bool ABF16>
__global__ __launch_bounds__(256, 2)
void fused_mlp(const float* __restrict__ zf, const unsigned short* __restrict__ zb,
               const int* __restrict__ eli, int E, int nnodes,
               const unsigned short* __restrict__ BTc,
               const float* __restrict__ b1, const float* __restrict__ W2,
               const float* __restrict__ b2, float* __restrict__ out)
{
    __shared__ unsigned short btile[2][4][128][32];   // [buf][slab][n][32] = 64 KB

    const int t = threadIdx.x;
    const int wid = t >> 6;
    const int lane = t & 63;
    const int l15 = lane & 15;
    const int quad = lane >> 4;
    const int m0 = blockIdx.x * 256 + wid * 64;

    // gather byte offsets for this lane's 4 src / 4 dst rows
    unsigned offs[4], offd[4];
#pragma unroll
    for (int mf = 0; mf < 4; ++mf) {
        int e = m0 + mf * 16 + l15;
        e = e < E ? e : E - 1;                 // clamp tail (stores masked later)
        int s = eli[e];
        int d = eli[E + e];
        s = s < 0 ? 0 : (s >= nnodes ? nnodes - 1 : s);
        d = d < 0 ? 0 : (d >= nnodes ? nnodes - 1 : d);
        offs[mf] = (unsigned)s * 512u;         // bf16 row = 512 B (fp32 path scales x2)
        offd[mf] = (unsigned)d * 512u;
    }
    const char* zbb = (const char*)(ABF16 ? (const void*)zb : (const void*)zf);

    const int swz = (l15 >> 1) & 3;
    const unsigned short* bbase = &btile[0][0][0][0] + l15 * 32 + (quad ^ swz) * 8;

    // ---- async stage of one 32 KB chunk (kc in [0,4)) into buf; zero VGPR cost ----
    auto stage = [&](int kc, int buf) {
        const char* g = (const char*)BTc + kc * 32768 + wid * 1024 + lane * 16;
        char* l = (char*)&btile[buf][0][0][0] + wid * 1024 + lane * 16;
#pragma unroll
        for (int i = 0; i < 8; ++i)
            gl_lds16(g + i * 4096, l + i * 4096);
    };

    // ---- A loader: ks in [0,16); src half (ks<8) or dst half ----
    // ABF16 path: 4 global loads per call; fp32 path: 8 (vmcnt counts below depend!).
    auto load_a = [&](int ks, short8* dst) {
        const unsigned* off = (ks < 8) ? offs : offd;
        if constexpr (ABF16) {
            const int cb = (ks & 7) * 64 + quad * 16;
#pragma unroll
            for (int mf = 0; mf < 4; ++mf)
                dst[mf] = *(const short8*)(zbb + (size_t)off[mf] + cb);
        } else {
            const int cb = (ks & 7) * 128 + quad * 32;
#pragma unroll
            for (int mf = 0; mf < 4; ++mf) {
                const float* pf = (const float*)(zbb + (size_t)off[mf] * 2 + cb);
                float4 f0 = *(const float4*)pf;
                float4 f1 = *(const float4*)(pf + 4);
                short8 av;
                av[0] = (short)bf16rne(f0.x); av[1] = (short)bf16rne(f0.y);
                av[2] = (short)bf16rne(f0.z); av[3] = (short)bf16rne(f0.w);
                av[4] = (short)bf16rne(f1.x); av[5] = (short)bf16rne(f1.y);
                av[6] = (short)bf16rne(f1.z); av[7] = (short)bf16rne(f1.w);
                dst[mf] = av;
            }
        }
    };

    floatx4 acc[4][8];
#pragma unroll
    for (int mf = 0; mf < 4; ++mf)
#pragma unroll
        for (int nf = 0; nf < 8; ++nf)
            acc[mf][nf] = (floatx4){0.f, 0.f, 0.f, 0.f};

    short8 A[4][4];                            // depth-4 rolling A prefetch (lookahead 3)

    // ---- prologue: stage chunk0 (issued FIRST: FIFO anchor), then 3 A-steps ----
    stage(0, 0);
    __builtin_amdgcn_sched_barrier(0);         // pin: staging issued before gathers
    load_a(0, A[0]);
    load_a(1, A[1]);
    load_a(2, A[2]);
    // counted drain: <=12 (bf16) / <=24 (fp32) outstanding => the 8 staging loads
    // completed; the 3 gather steps stay in flight across the barrier.
    if constexpr (ABF16) asm volatile("s_waitcnt vmcnt(12)" ::: "memory");
    else                 asm volatile("s_waitcnt vmcnt(24)" ::: "memory");
    __builtin_amdgcn_s_barrier();
    __builtin_amdgcn_sched_barrier(0);

#pragma unroll
    for (int kc = 0; kc < 4; ++kc) {           // 4 chunks of BK=128
        if (kc < 3) {
            stage(kc + 1, (kc + 1) & 1);
            __builtin_amdgcn_sched_barrier(0); // staging before this iter's gathers
        }

#pragma unroll
        for (int s4 = 0; s4 < 4; ++s4) {
            const int ks = kc * 4 + s4;
            if (ks + 3 < 16) load_a(ks + 3, A[(ks + 3) & 3]);

            const unsigned short* bs = bbase + (kc & 1) * 16384 + s4 * 4096;
            const short8* ac = A[ks & 3];

            short8 bfr[4];                     // 2x4 split keeps arch VGPR ~112
#pragma unroll
            for (int nf = 0; nf < 4; ++nf)
                bfr[nf] = *(const short8*)(bs + nf * 512);      // swizzled: 0 conflicts
#pragma unroll
            for (int nf = 0; nf < 4; ++nf)
#pragma unroll
                for (int mf = 0; mf < 4; ++mf)
                    acc[mf][nf] = __builtin_amdgcn_mfma_f32_16x16x32_bf16(
                        ac[mf], bfr[nf], acc[mf][nf], 0, 0, 0);
#pragma unroll
            for (int nf = 0; nf < 4; ++nf)
                bfr[nf] = *(const short8*)(bs + (nf + 4) * 512);
#pragma unroll
            for (int nf = 0; nf < 4; ++nf)
#pragma unroll
                for (int mf = 0; mf < 4; ++mf)
                    acc[mf][nf + 4] = __builtin_amdgcn_mfma_f32_16x16x32_bf16(
                        ac[mf], bfr[nf], acc[mf][nf + 4], 0, 0, 0);
        }

        if (kc < 3) {
            // Counted barrier: 16 (bf16) / 32 (fp32) gathers were issued after this
            // iteration's staging => waiting to that depth proves staging landed,
            // without draining the in-flight A lookahead. (The s4=3 MFMA consumption
            // already implies this in practice; the explicit wait is the guarantee.)
            if constexpr (ABF16) asm volatile("s_waitcnt vmcnt(16)" ::: "memory");
            else                 asm volatile("s_waitcnt vmcnt(32)" ::: "memory");
            __builtin_amdgcn_s_barrier();      // publish buf (kc+1)&1
            __builtin_amdgcn_sched_barrier(0); // no ds_read hoists above the barrier
        }
    }

    // ---- epilogue (consts loaded late; C/D: col=lane&15+16nf, row=quad*4+r+16mf) ----
    const float b2s = b2[0];
    float b1v[8], w2v[8];
#pragma unroll
    for (int nf = 0; nf < 8; ++nf) {
        int c = nf * 16 + l15;
        b1v[nf] = b1[c];
        w2v[nf] = W2[c];
    }
#pragma unroll
    for (int mf = 0; mf < 4; ++mf) {
#pragma unroll
        for (int r = 0; r < 4; ++r) {
            float s = 0.f;
#pragma unroll
            for (int nf = 0; nf < 8; ++nf) {
                float v = acc[mf][nf][r] + b1v[nf];
                v = v > 0.f ? v : 0.f;
                s = fmaf(v, w2v[nf], s);
            }
            s += __shfl_xor(s, 1);
            s += __shfl_xor(s, 2);
            s += __shfl_xor(s, 4);
            s += __shfl_xor(s, 8);
            if (l15 == 0) {
                int e = m0 + mf * 16 + quad * 4 + r;
                if (e < E) out[e] = s + b2s;
            }
        }
    }
}

// ---- emergency fallback (tiny ws): one block per edge, fp32 vector ----
__global__ void naive_edge(const float* __restrict__ z, const int* __restrict__ eli,
                           int E, int nnodes,
                           const float* __restrict__ W1, const float* __restrict__ b1,
                           const float* __restrict__ W2, const float* __restrict__ b2,
                           float* __restrict__ out)
{
    __shared__ float red[2];
    int e = blockIdx.x;
    int j = threadIdx.x;
    int s = eli[e], d = eli[E + e];
    s = s < 0 ? 0 : (s >= nnodes ? nnodes - 1 : s);
    d = d < 0 ? 0 : (d >= nnodes ? nnodes - 1 : d);
    const float* zs = z + (long long)s * 256;
    const float* zd = z + (long long)d * 256;
    float h = b1[j];
    for (int i = 0; i < 256; ++i) h = fmaf(zs[i], W1[i * 128 + j], h);
    for (int i = 0; i < 256; ++i) h = fmaf(zd[i], W1[(256 + i) * 128 + j], h);
    h = h > 0.f ? h : 0.f;
    float v = h * W2[j];
    v += __shfl_xor(v, 1);  v += __shfl_xor(v, 2);  v += __shfl_xor(v, 4);
    v += __shfl_xor(v, 8);  v += __shfl_xor(v, 16); v += __shfl_xor(v, 32);
    if ((threadIdx.x & 63) == 0) red[threadIdx.x >> 6] = v;
    __syncthreads();
    if (threadIdx.x == 0) out[e] = red[0] + red[1] + b2[0];
}

extern "C" void kernel_launch(void* const* d_in, const int* in_sizes, int n_in,
                              void* d_out, int out_size, void* d_ws, size_t ws_size,
                              hipStream_t stream) {
    const float* z   = (const float*)d_in[0];
    const int*   eli = (const int*)d_in[1];      // int64 in reference -> int32 on device
    const float* W1  = (const float*)d_in[2];
    const float* b1  = (const float*)d_in[3];
    const float* W2  = (const float*)d_in[4];
    const float* b2  = (const float*)d_in[5];
    float*       out = (float*)d_out;

    const int E      = in_sizes[1] / 2;
    const int nnodes = in_sizes[0] / 256;

    const size_t ZB  = (size_t)nnodes * 256 * 2;   // z in bf16
    const size_t BTB = (size_t)512 * 128 * 2;      // B^T (swizzled linear image)

    const int grid_main = (E + 255) / 256;

    if (ws_size >= ZB + BTB) {
        unsigned short* zb  = (unsigned short*)d_ws;
        unsigned short* BTc = (unsigned short*)((char*)d_ws + ZB);
        int n4 = nnodes * 64;
        cvt_z<<<(n4 + 255) / 256, 256, 0, stream>>>(z, zb, n4);
        cvt_w1<<<256, 256, 0, stream>>>(W1, BTc);
        fused_mlp<true><<<grid_main, 256, 0, stream>>>(nullptr, zb, eli, E, nnodes, BTc, b1, W2, b2, out);
    } else if (ws_size >= BTB) {
        unsigned short* BTc = (unsigned short*)d_ws;
        cvt_w1<<<256, 256, 0, stream>>>(W1, BTc);
        fused_mlp<false><<<grid_main, 256, 0, stream>>>(z, nullptr, eli, E, nnodes, BTc, b1, W2, b2, out);
    } else {
        naive_edge<<<E, 128, 0, stream>>>(z, eli, E, nnodes, W1, b1, W2, b2, out);
    }
}

// Round 2
// 260.409 us; speedup vs baseline: 1.3686x; 1.3686x over previous
//
#include <hip/hip_runtime.h>
#include <hip/hip_bf16.h>

// LinkPredictorGAT: out[e] = relu(concat(z[src[e]], z[dst[e]]) @ W1 + b1) @ W2 + b2
// R10 = algorithmic refactor. h distributes over the concat:
//   h = z[src]@W1a + z[dst]@W1b   (W1a = W1[0:256], W1b = W1[256:512])
// so precompute ONCE per node (13.1 GFLOP dense GEMM, contiguous A):
//   H[n][0:128]   = z[n]@W1a + b1   (fp16)
//   H[n][128:256] = z[n]@W1b        (fp16)
// then the edge phase is a pure streaming gather (2 x 256 B per edge, HALF of R8's
// 2 x 512 B z-gather) with no MFMA at all:
//   out[e] = relu(H[src][0:128] + H[dst][128:256]) . W2 + b2
// This removes the per-edge 131 GFLOP GEMM (floor 63us) entirely and halves gather
// traffic. fp16 (not bf16) H keeps absmax ~unchanged (~0.0156).
// R9 post-mortem: counted-vmcnt + depth-4 lookahead REGRESSED (194->204us, FETCH
// +50MB: lookahead spread killed L2 locality; sched_barriers disturbed the compiler
// schedule). All R9 deltas reverted; gemm_h uses the proven R8 skeleton.

typedef __attribute__((ext_vector_type(4))) float floatx4;
typedef __attribute__((ext_vector_type(8))) short short8;
typedef _Float16 half8v __attribute__((ext_vector_type(8)));

__device__ __forceinline__ unsigned short bf16rne(float x) {
    unsigned int u = __float_as_uint(x);
    u += 0x7fffu + ((u >> 16) & 1u);
    return (unsigned short)(u >> 16);
}

// async global->LDS, 16 B per lane; LDS dest = wave-uniform base + lane*16.
__device__ __forceinline__ void gl_lds16(const void* g, void* l) {
    __builtin_amdgcn_global_load_lds(
        (const __attribute__((address_space(1))) void*)(unsigned long long)g,
        (__attribute__((address_space(3))) void*)(unsigned)(unsigned long long)l,
        16, 0, 0);
}

// ---- convert z (fp32 -> bf16), float4 per thread ----
__global__ void cvt_z(const float* __restrict__ z, unsigned short* __restrict__ zb, int n4) {
    int i = blockIdx.x * blockDim.x + threadIdx.x;
    if (i < n4) {
        float4 f = ((const float4*)z)[i];
        ushort4 u;
        u.x = bf16rne(f.x); u.y = bf16rne(f.y);
        u.z = bf16rne(f.z); u.w = bf16rne(f.w);
        ((ushort4*)zb)[i] = u;
    }
}

// ---- W1 [512][128] fp32 -> BTc2: two per-half swizzled linear images ----
// Per half (k_local in [0,256)): L(s,n,g',j) = s*4096 + n*32 + g'*8 + j shorts;
// s = k_local>>5, g = (k_local>>3)&3, j = k_local&7, g' = g ^ ((n>>1)&3).
// Half h occupies shorts [h*32768, h*32768+32768). Reader: 0 bank conflicts.
__global__ void cvt_w1h(const float* __restrict__ W1, unsigned short* __restrict__ BTc2) {
    int t = blockIdx.x * blockDim.x + threadIdx.x;   // 0..65535
    int hf = t >> 15, rem = t & 32767;
    int s = rem >> 12, rem2 = rem & 4095;
    int n = rem2 >> 5, rem3 = rem2 & 31;
    int gp = rem3 >> 3, j = rem3 & 7;
    int g = gp ^ ((n >> 1) & 3);
    int k = hf * 256 + s * 32 + g * 8 + j;
    BTc2[t] = bf16rne(W1[k * 128 + n]);
}

// ---- old-path W1 image (512 rows), kept for the low-workspace fallback ----
__global__ void cvt_w1(const float* __restrict__ W1, unsigned short* __restrict__ BTc) {
    int t = blockIdx.x * blockDim.x + threadIdx.x;   // 0..65535
    int s = t >> 12, rem = t & 4095;
    int n = rem >> 5, rem2 = rem & 31;
    int gp = rem2 >> 3, j = rem2 & 7;
    int g = gp ^ ((n >> 1) & 3);
    int k = s * 32 + g * 8 + j;
    BTc[t] = bf16rne(W1[k * 128 + n]);
}

// ---- precompute GEMM: H[row][half*128 + c] = z[row] @ W1[half*256 : , c] (+b1 if half==0) ----
// R8 skeleton: 256 thr / 4 waves, each wave 64 rows x 128 cols; K=256 as 2 chunks of
// BK=128; double-buffered swizzled LDS B (64 KB); global_load_lds width=16 staging;
// depth-3 rolling A prefetch; plain __syncthreads (R9's counted vmcnt reverted).
template <bool ABF16>
__global__ __launch_bounds__(256, 2)
void gemm_h(const float* __restrict__ zf, const unsigned short* __restrict__ zb,
            int nnodes, const unsigned short* __restrict__ BTc2,
            const float* __restrict__ b1, _Float16* __restrict__ Hh)
{
    __shared__ unsigned short btile[2][4][128][32];   // 64 KB -> 2 blocks/CU

    const int t = threadIdx.x;
    const int wid = t >> 6;
    const int lane = t & 63;
    const int l15 = lane & 15;
    const int quad = lane >> 4;
    const int m0 = blockIdx.x * 256 + wid * 64;
    const int hf = blockIdx.y;                        // 0: W1a+b1, 1: W1b

    unsigned offs[4];
#pragma unroll
    for (int mf = 0; mf < 4; ++mf) {
        int r = m0 + mf * 16 + l15;
        r = r < nnodes ? r : nnodes - 1;              // clamp tail (stores masked)
        offs[mf] = (unsigned)r * 512u;                // bf16 row = 512 B (fp32 x2 at use)
    }
    const char* zbb = (const char*)(ABF16 ? (const void*)zb : (const void*)zf);

    const int swz = (l15 >> 1) & 3;
    const unsigned short* bbase = &btile[0][0][0][0] + l15 * 32 + (quad ^ swz) * 8;

    auto stage = [&](int kc, int buf) {
        const char* g = (const char*)BTc2 + hf * 65536 + kc * 32768 + wid * 1024 + lane * 16;
        char* l = (char*)&btile[buf][0][0][0] + wid * 1024 + lane * 16;
#pragma unroll
        for (int i = 0; i < 8; ++i)
            gl_lds16(g + i * 4096, l + i * 4096);
    };

    auto load_a = [&](int ks, short8* dst) {          // ks in [0,8)
        if constexpr (ABF16) {
            const int cb = ks * 64 + quad * 16;
#pragma unroll
            for (int mf = 0; mf < 4; ++mf)
                dst[mf] = *(const short8*)(zbb + (size_t)offs[mf] + cb);
        } else {
            const int cb = ks * 128 + quad * 32;
#pragma unroll
            for (int mf = 0; mf < 4; ++mf) {
                const float* pf = (const float*)(zbb + (size_t)offs[mf] * 2 + cb);
                float4 f0 = *(const float4*)pf;
                float4 f1 = *(const float4*)(pf + 4);
                short8 av;
                av[0] = (short)bf16rne(f0.x); av[1] = (short)bf16rne(f0.y);
                av[2] = (short)bf16rne(f0.z); av[3] = (short)bf16rne(f0.w);
                av[4] = (short)bf16rne(f1.x); av[5] = (short)bf16rne(f1.y);
                av[6] = (short)bf16rne(f1.z); av[7] = (short)bf16rne(f1.w);
                dst[mf] = av;
            }
        }
    };

    floatx4 acc[4][8];
#pragma unroll
    for (int mf = 0; mf < 4; ++mf)
#pragma unroll
        for (int nf = 0; nf < 8; ++nf)
            acc[mf][nf] = (floatx4){0.f, 0.f, 0.f, 0.f};

    short8 A[3][4];
    stage(0, 0);
    load_a(0, A[0]);
    load_a(1, A[1]);
    __syncthreads();

#pragma unroll
    for (int kc = 0; kc < 2; ++kc) {
        if (kc == 0) stage(1, 1);

#pragma unroll
        for (int s4 = 0; s4 < 4; ++s4) {
            const int ks = kc * 4 + s4;
            if (ks + 2 < 8) load_a(ks + 2, A[(ks + 2) % 3]);

            const unsigned short* bs = bbase + kc * 16384 + s4 * 4096;
            const short8* ac = A[ks % 3];

            short8 bfr[4];
#pragma unroll
            for (int nf = 0; nf < 4; ++nf)
                bfr[nf] = *(const short8*)(bs + nf * 512);       // swizzled: 0 conflicts
#pragma unroll
            for (int nf = 0; nf < 4; ++nf)
#pragma unroll
                for (int mf = 0; mf < 4; ++mf)
                    acc[mf][nf] = __builtin_amdgcn_mfma_f32_16x16x32_bf16(
                        ac[mf], bfr[nf], acc[mf][nf], 0, 0, 0);
#pragma unroll
            for (int nf = 0; nf < 4; ++nf)
                bfr[nf] = *(const short8*)(bs + (nf + 4) * 512);
#pragma unroll
            for (int nf = 0; nf < 4; ++nf)
#pragma unroll
                for (int mf = 0; mf < 4; ++mf)
                    acc[mf][nf + 4] = __builtin_amdgcn_mfma_f32_16x16x32_bf16(
                        ac[mf], bfr[nf], acc[mf][nf + 4], 0, 0, 0);
        }

        if (kc == 0) __syncthreads();
    }

    // epilogue: C/D col = l15 + 16nf, row-in-tile = quad*4 + r (+16mf). Store fp16.
    float b1v[8];
#pragma unroll
    for (int nf = 0; nf < 8; ++nf)
        b1v[nf] = (hf == 0) ? b1[nf * 16 + l15] : 0.f;
#pragma unroll
    for (int mf = 0; mf < 4; ++mf) {
#pragma unroll
        for (int r = 0; r < 4; ++r) {
            int row = m0 + mf * 16 + quad * 4 + r;
            if (row < nnodes) {
                _Float16* hp = Hh + (size_t)row * 256 + hf * 128 + l15;
#pragma unroll
                for (int nf = 0; nf < 8; ++nf)
                    hp[nf * 16] = (_Float16)(acc[mf][nf][r] + b1v[nf]);
            }
        }
    }
}

// ---- edge phase: pure gather + relu-dot. 16 lanes/edge, 4 edges/wave-step, 4 steps.
// Block = 256 thr covers 64 edges. No LDS, ~60 VGPR -> 8 waves/SIMD for latency hiding.
__global__ __launch_bounds__(256)
void edge_out(const _Float16* __restrict__ Hh, const int* __restrict__ eli,
              int E, int nnodes,
              const float* __restrict__ W2, const float* __restrict__ b2,
              float* __restrict__ out)
{
    const int t = threadIdx.x;
    const int lane = t & 63;
    const int wid = t >> 6;
    const int l15 = lane & 15;
    const int grp = lane >> 4;

    float w2v[8];
#pragma unroll
    for (int j = 0; j < 8; ++j)
        w2v[j] = W2[l15 * 8 + j];
    const float b2s = b2[0];

    const int e0 = blockIdx.x * 64 + wid * 16 + grp;

    half8v hs[4], hd[4];
    int ee[4];
#pragma unroll
    for (int i = 0; i < 4; ++i) {
        int e = e0 + i * 4;
        ee[i] = e;
        int ec = e < E ? e : E - 1;
        int s = eli[ec];
        int d = eli[E + ec];
        s = s < 0 ? 0 : (s >= nnodes ? nnodes - 1 : s);
        d = d < 0 ? 0 : (d >= nnodes ? nnodes - 1 : d);
        hs[i] = *(const half8v*)(Hh + (size_t)s * 256 + l15 * 8);
        hd[i] = *(const half8v*)(Hh + (size_t)d * 256 + 128 + l15 * 8);
    }
#pragma unroll
    for (int i = 0; i < 4; ++i) {
        float sacc = 0.f;
#pragma unroll
        for (int j = 0; j < 8; ++j) {
            float v = (float)hs[i][j] + (float)hd[i][j];
            v = v > 0.f ? v : 0.f;
            sacc = fmaf(v, w2v[j], sacc);
        }
        sacc += __shfl_xor(sacc, 1);
        sacc += __shfl_xor(sacc, 2);
        sacc += __shfl_xor(sacc, 4);
        sacc += __shfl_xor(sacc, 8);
        if (l15 == 0 && ee[i] < E)
            out[ee[i]] = sacc + b2s;
    }
}

// ---- R8 fused kernel (fp32-A variant), kept for the low-workspace fallback ----
template <bool ABF16>
__global__ __launch_bounds__(256, 2)
void fused_mlp(const float* __restrict__ zf, const unsigned short* __restrict__ zb,
               const int* __restrict__ eli, int E, int nnodes,
               const unsigned short* __restrict__ BTc,
               const float* __restrict__ b1, const float* __restrict__ W2,
               const float* __restrict__ b2, float* __restrict__ out)
{
    __shared__ unsigned short btile[2][4][128][32];

    const int t = threadIdx.x;
    const int wid = t >> 6;
    const int lane = t & 63;
    const int l15 = lane & 15;
    const int quad = lane >> 4;
    const int m0 = blockIdx.x * 256 + wid * 64;

    unsigned offs[4], offd[4];
#pragma unroll
    for (int mf = 0; mf < 4; ++mf) {
        int e = m0 + mf * 16 + l15;
        e = e < E ? e : E - 1;
        int s = eli[e];
        int d = eli[E + e];
        s = s < 0 ? 0 : (s >= nnodes ? nnodes - 1 : s);
        d = d < 0 ? 0 : (d >= nnodes ? nnodes - 1 : d);
        offs[mf] = (unsigned)s * 512u;
        offd[mf] = (unsigned)d * 512u;
    }
    const char* zbb = (const char*)(ABF16 ? (const void*)zb : (const void*)zf);

    const int swz = (l15 >> 1) & 3;
    const unsigned short* bbase = &btile[0][0][0][0] + l15 * 32 + (quad ^ swz) * 8;

    auto stage = [&](int kc, int buf) {
        const char* g = (const char*)BTc + kc * 32768 + wid * 1024 + lane * 16;
        char* l = (char*)&btile[buf][0][0][0] + wid * 1024 + lane * 16;
#pragma unroll
        for (int i = 0; i < 8; ++i)
            gl_lds16(g + i * 4096, l + i * 4096);
    };

    auto load_a = [&](int ks, short8* dst) {
        const unsigned* off = (ks < 8) ? offs : offd;
        if constexpr (ABF16) {
            const int cb = (ks & 7) * 64 + quad * 16;
#pragma unroll
            for (int mf = 0; mf < 4; ++mf)
                dst[mf] = *(const short8*)(zbb + (size_t)off[mf] + cb);
        } else {
            const int cb = (ks & 7) * 128 + quad * 32;
#pragma unroll
            for (int mf = 0; mf < 4; ++mf) {
                const float* pf = (const float*)(zbb + (size_t)off[mf] * 2 + cb);
                float4 f0 = *(const float4*)pf;
                float4 f1 = *(const float4*)(pf + 4);
                short8 av;
                av[0] = (short)bf16rne(f0.x); av[1] = (short)bf16rne(f0.y);
                av[2] = (short)bf16rne(f0.z); av[3] = (short)bf16rne(f0.w);
                av[4] = (short)bf16rne(f1.x); av[5] = (short)bf16rne(f1.y);
                av[6] = (short)bf16rne(f1.z); av[7] = (short)bf16rne(f1.w);
                dst[mf] = av;
            }
        }
    };

    floatx4 acc[4][8];
#pragma unroll
    for (int mf = 0; mf < 4; ++mf)
#pragma unroll
        for (int nf = 0; nf < 8; ++nf)
            acc[mf][nf] = (floatx4){0.f, 0.f, 0.f, 0.f};

    short8 A[3][4];
    stage(0, 0);
    load_a(0, A[0]);
    load_a(1, A[1]);
    __syncthreads();

#pragma unroll
    for (int kc = 0; kc < 4; ++kc) {
        if (kc < 3) stage(kc + 1, (kc + 1) & 1);

#pragma unroll
        for (int s4 = 0; s4 < 4; ++s4) {
            const int ks = kc * 4 + s4;
            if (ks + 2 < 16) load_a(ks + 2, A[(ks + 2) % 3]);

            const unsigned short* bs = bbase + (kc & 1) * 16384 + s4 * 4096;
            short8 bfr[8];
#pragma unroll
            for (int nf = 0; nf < 8; ++nf)
                bfr[nf] = *(const short8*)(bs + nf * 512);

            const short8* ac = A[ks % 3];
#pragma unroll
            for (int nf = 0; nf < 8; ++nf)
#pragma unroll
                for (int mf = 0; mf < 4; ++mf)
                    acc[mf][nf] = __builtin_amdgcn_mfma_f32_16x16x32_bf16(
                        ac[mf], bfr[nf], acc[mf][nf], 0, 0, 0);
        }

        if (kc < 3) __syncthreads();
    }

    const float b2s = b2[0];
    float b1v[8], w2v[8];
#pragma unroll
    for (int nf = 0; nf < 8; ++nf) {
        int c = nf * 16 + l15;
        b1v[nf] = b1[c];
        w2v[nf] = W2[c];
    }
#pragma unroll
    for (int mf = 0; mf < 4; ++mf) {
#pragma unroll
        for (int r = 0; r < 4; ++r) {
            float s = 0.f;
#pragma unroll
            for (int nf = 0; nf < 8; ++nf) {
                float v = acc[mf][nf][r] + b1v[nf];
                v = v > 0.f ? v : 0.f;
                s = fmaf(v, w2v[nf], s);
            }
            s += __shfl_xor(s, 1);
            s += __shfl_xor(s, 2);
            s += __shfl_xor(s, 4);
            s += __shfl_xor(s, 8);
            if (l15 == 0) {
                int e = m0 + mf * 16 + quad * 4 + r;
                if (e < E) out[e] = s + b2s;
            }
        }
    }
}

// ---- emergency fallback (tiny ws): one block per edge, fp32 vector ----
__global__ void naive_edge(const float* __restrict__ z, const int* __restrict__ eli,
                           int E, int nnodes,
                           const float* __restrict__ W1, const float* __restrict__ b1,
                           const float* __restrict__ W2, const float* __restrict__ b2,
                           float* __restrict__ out)
{
    __shared__ float red[2];
    int e = blockIdx.x;
    int j = threadIdx.x;
    int s = eli[e], d = eli[E + e];
    s = s < 0 ? 0 : (s >= nnodes ? nnodes - 1 : s);
    d = d < 0 ? 0 : (d >= nnodes ? nnodes - 1 : d);
    const float* zs = z + (long long)s * 256;
    const float* zd = z + (long long)d * 256;
    float h = b1[j];
    for (int i = 0; i < 256; ++i) h = fmaf(zs[i], W1[i * 128 + j], h);
    for (int i = 0; i < 256; ++i) h = fmaf(zd[i], W1[(256 + i) * 128 + j], h);
    h = h > 0.f ? h : 0.f;
    float v = h * W2[j];
    v += __shfl_xor(v, 1);  v += __shfl_xor(v, 2);  v += __shfl_xor(v, 4);
    v += __shfl_xor(v, 8);  v += __shfl_xor(v, 16); v += __shfl_xor(v, 32);
    if ((threadIdx.x & 63) == 0) red[threadIdx.x >> 6] = v;
    __syncthreads();
    if (threadIdx.x == 0) out[e] = red[0] + red[1] + b2[0];
}

extern "C" void kernel_launch(void* const* d_in, const int* in_sizes, int n_in,
                              void* d_out, int out_size, void* d_ws, size_t ws_size,
                              hipStream_t stream) {
    const float* z   = (const float*)d_in[0];
    const int*   eli = (const int*)d_in[1];      // int64 in reference -> int32 on device
    const float* W1  = (const float*)d_in[2];
    const float* b1  = (const float*)d_in[3];
    const float* W2  = (const float*)d_in[4];
    const float* b2  = (const float*)d_in[5];
    float*       out = (float*)d_out;

    const int E      = in_sizes[1] / 2;
    const int nnodes = in_sizes[0] / 256;

    const size_t ZB   = (size_t)nnodes * 512;    // z in bf16
    const size_t HB   = (size_t)nnodes * 512;    // H partials fp16 [N][256]
    const size_t BT2B = 131072;                  // two-half swizzled W1 image
    const size_t BTB  = (size_t)512 * 128 * 2;   // old single image (fallback)

    const int grid_gemm = (nnodes + 255) / 256;
    const int grid_edge = (E + 63) / 64;

    if (ws_size >= ZB + HB + BT2B) {
        // primary: bf16 z staging + precompute GEMM + pure-gather edge phase
        unsigned short* zb   = (unsigned short*)d_ws;
        _Float16*       Hh   = (_Float16*)((char*)d_ws + ZB);
        unsigned short* BTc2 = (unsigned short*)((char*)d_ws + ZB + HB);
        int n4 = nnodes * 64;
        cvt_z<<<(n4 + 255) / 256, 256, 0, stream>>>(z, zb, n4);
        cvt_w1h<<<256, 256, 0, stream>>>(W1, BTc2);
        gemm_h<true><<<dim3(grid_gemm, 2), 256, 0, stream>>>(nullptr, zb, nnodes, BTc2, b1, Hh);
        edge_out<<<grid_edge, 256, 0, stream>>>(Hh, eli, E, nnodes, W2, b2, out);
    } else if (ws_size >= HB + BT2B) {
        // same plan, GEMM reads z fp32 directly (old-footprint workspace)
        _Float16*       Hh   = (_Float16*)d_ws;
        unsigned short* BTc2 = (unsigned short*)((char*)d_ws + HB);
        cvt_w1h<<<256, 256, 0, stream>>>(W1, BTc2);
        gemm_h<false><<<dim3(grid_gemm, 2), 256, 0, stream>>>(z, nullptr, nnodes, BTc2, b1, Hh);
        edge_out<<<grid_edge, 256, 0, stream>>>(Hh, eli, E, nnodes, W2, b2, out);
    } else if (ws_size >= BTB) {
        unsigned short* BTc = (unsigned short*)d_ws;
        cvt_w1<<<256, 256, 0, stream>>>(W1, BTc);
        fused_mlp<false><<<(E + 255) / 256, 256, 0, stream>>>(z, nullptr, eli, E, nnodes, BTc, b1, W2, b2, out);
    } else {
        naive_edge<<<E, 128, 0, stream>>>(z, eli, E, nnodes, W1, b1, W2, b2, out);
    }
}

// Round 3
// 247.106 us; speedup vs baseline: 1.4423x; 1.0538x over previous
//
#include <hip/hip_runtime.h>
#include <hip/hip_bf16.h>

// LinkPredictorGAT: out[e] = relu(concat(z[src[e]], z[dst[e]]) @ W1 + b1) @ W2 + b2
// R11 = R10's factorization (per-node H precompute + pure-gather edge phase) with the
// pre-phase redundancy removed:
//   - cvt_z DELETED: gemm_hb reads fp32 z directly and converts to bf16 in-register
//     (same RNE bits as cvt_z -> identical numerics, absmax unchanged).
//   - both H halves computed in ONE block (they share the same A row z[n]): wave tile
//     32 rows x 256 cols (mf=2, nf=16, acc=128 AGPR unchanged), BK=64 chunks with both
//     halves' B staged (2x16KB), double-buffered = 64 KB LDS, 2 blocks/CU.
//   Pre-phase traffic: ~300 MB -> ~151 MB, and one fewer launch.
// edge_out is byte-identical to R10 (69us, FETCH 234MB, the next target: src-bucketing).

typedef __attribute__((ext_vector_type(4))) float floatx4;
typedef __attribute__((ext_vector_type(8))) short short8;
typedef _Float16 half8v __attribute__((ext_vector_type(8)));

__device__ __forceinline__ unsigned short bf16rne(float x) {
    unsigned int u = __float_as_uint(x);
    u += 0x7fffu + ((u >> 16) & 1u);
    return (unsigned short)(u >> 16);
}

// async global->LDS, 16 B per lane; LDS dest = wave-uniform base + lane*16.
__device__ __forceinline__ void gl_lds16(const void* g, void* l) {
    __builtin_amdgcn_global_load_lds(
        (const __attribute__((address_space(1))) void*)(unsigned long long)g,
        (__attribute__((address_space(3))) void*)(unsigned)(unsigned long long)l,
        16, 0, 0);
}

// ---- W1 [512][128] fp32 -> BTc2: two per-half swizzled linear images ----
// Per half (k_local in [0,256)): L(s,n,g',j) = s*4096 + n*32 + g'*8 + j shorts;
// s = k_local>>5, g = (k_local>>3)&3, j = k_local&7, g' = g ^ ((n>>1)&3).
// Half h occupies shorts [h*32768, +32768). Reader: 0 bank conflicts (R6/R7-verified).
__global__ void cvt_w1h(const float* __restrict__ W1, unsigned short* __restrict__ BTc2) {
    int t = blockIdx.x * blockDim.x + threadIdx.x;   // 0..65535
    int hf = t >> 15, rem = t & 32767;
    int s = rem >> 12, rem2 = rem & 4095;
    int n = rem2 >> 5, rem3 = rem2 & 31;
    int gp = rem3 >> 3, j = rem3 & 7;
    int g = gp ^ ((n >> 1) & 3);
    int k = hf * 256 + s * 32 + g * 8 + j;
    BTc2[t] = bf16rne(W1[k * 128 + n]);
}

// ---- old-path W1 image (512 rows), kept for the low-workspace fallback ----
__global__ void cvt_w1(const float* __restrict__ W1, unsigned short* __restrict__ BTc) {
    int t = blockIdx.x * blockDim.x + threadIdx.x;   // 0..65535
    int s = t >> 12, rem = t & 4095;
    int n = rem >> 5, rem2 = rem & 31;
    int gp = rem2 >> 3, j = rem2 & 7;
    int g = gp ^ ((n >> 1) & 3);
    int k = s * 32 + g * 8 + j;
    BTc[t] = bf16rne(W1[k * 128 + n]);
}

// ---- precompute GEMM, both halves per block ----
// H[row][0:128] = z[row]@W1a + b1 ; H[row][128:256] = z[row]@W1b  (fp16 out)
// 256 thr / 4 waves; wave = 32 rows x 256 cols (mf=2, nf=16); block = 128 rows.
// K=256 as 4 chunks of BK=64; per chunk both halves' B staged (2 x 16 KB);
// double-buffered = 64 KB -> 2 blocks/CU. A read fp32, converted in-register.
__global__ __launch_bounds__(256, 2)
void gemm_hb(const float* __restrict__ zf, int nnodes,
             const unsigned short* __restrict__ BTc2,
             const float* __restrict__ b1, _Float16* __restrict__ Hh)
{
    // [buf][half][slab(K32)][n(128)][32] shorts = 64 KB
    __shared__ unsigned short btile[2][2][2][128][32];

    const int t = threadIdx.x;
    const int wid = t >> 6;
    const int lane = t & 63;
    const int l15 = lane & 15;
    const int quad = lane >> 4;
    const int m0 = blockIdx.x * 128 + wid * 32;

    unsigned offs[2];
#pragma unroll
    for (int mf = 0; mf < 2; ++mf) {
        int r = m0 + mf * 16 + l15;
        r = r < nnodes ? r : nnodes - 1;              // clamp tail (stores masked)
        offs[mf] = (unsigned)r * 1024u;               // fp32 row = 1024 B
    }
    const char* zbb = (const char*)zf;

    const int swz = (l15 >> 1) & 3;
    const unsigned short* bbase = &btile[0][0][0][0][0] + l15 * 32 + (quad ^ swz) * 8;

    // stage chunk kc (BK=64: 2 slabs per half, 16 KB per half) into buf
    auto stage = [&](int kc, int buf) {
        char* lbase = (char*)&btile[0][0][0][0][0] + buf * 32768 + wid * 1024 + lane * 16;
        const char* gbase = (const char*)BTc2 + kc * 16384 + wid * 1024 + lane * 16;
#pragma unroll
        for (int h = 0; h < 2; ++h) {
            const char* g = gbase + h * 65536;
            char* l = lbase + h * 16384;
#pragma unroll
            for (int i = 0; i < 4; ++i)
                gl_lds16(g + i * 4096, l + i * 4096);
        }
    };

    // A loader: K-step ks in [0,8) (K32 each); fp32 -> bf16 in-register (RNE)
    auto load_a = [&](int ks, short8* dst) {
        const int cb = ks * 128 + quad * 32;
#pragma unroll
        for (int mf = 0; mf < 2; ++mf) {
            const float* pf = (const float*)(zbb + (size_t)offs[mf] + cb);
            float4 f0 = *(const float4*)pf;
            float4 f1 = *(const float4*)(pf + 4);
            short8 av;
            av[0] = (short)bf16rne(f0.x); av[1] = (short)bf16rne(f0.y);
            av[2] = (short)bf16rne(f0.z); av[3] = (short)bf16rne(f0.w);
            av[4] = (short)bf16rne(f1.x); av[5] = (short)bf16rne(f1.y);
            av[6] = (short)bf16rne(f1.z); av[7] = (short)bf16rne(f1.w);
            dst[mf] = av;
        }
    };

    floatx4 acc[2][16];
#pragma unroll
    for (int mf = 0; mf < 2; ++mf)
#pragma unroll
        for (int nf = 0; nf < 16; ++nf)
            acc[mf][nf] = (floatx4){0.f, 0.f, 0.f, 0.f};

    short8 A[3][2];                                   // depth-3 rolling A prefetch
    stage(0, 0);
    load_a(0, A[0]);
    load_a(1, A[1]);
    __syncthreads();

#pragma unroll
    for (int kc = 0; kc < 4; ++kc) {                  // 4 chunks of BK=64
        if (kc < 3) stage(kc + 1, (kc + 1) & 1);

#pragma unroll
        for (int s4 = 0; s4 < 2; ++s4) {              // 2 K32 slabs per chunk
            const int ks = kc * 2 + s4;
            if (ks + 2 < 8) load_a(ks + 2, A[(ks + 2) % 3]);

            const unsigned short* bs0 = bbase + (kc & 1) * 16384 + s4 * 4096;  // half0
            const short8* ac = A[ks % 3];

#pragma unroll
            for (int gq = 0; gq < 4; ++gq) {          // 4 groups of 4 nf (2 per half)
                const unsigned short* bs = bs0 + (gq >> 1) * 8192 + (gq & 1) * 2048;
                short8 bfr[4];
#pragma unroll
                for (int nf = 0; nf < 4; ++nf)
                    bfr[nf] = *(const short8*)(bs + nf * 512);  // swizzled: 0 conflicts
#pragma unroll
                for (int nf = 0; nf < 4; ++nf)
#pragma unroll
                    for (int mf = 0; mf < 2; ++mf)
                        acc[mf][gq * 4 + nf] = __builtin_amdgcn_mfma_f32_16x16x32_bf16(
                            ac[mf], bfr[nf], acc[mf][gq * 4 + nf], 0, 0, 0);
            }
        }

        if (kc < 3) __syncthreads();
    }

    // epilogue: C/D col = l15 + 16*(nf&7), half = nf>>3; row = quad*4 + r (+16mf)
    float b1v[8];
#pragma unroll
    for (int nf = 0; nf < 8; ++nf)
        b1v[nf] = b1[nf * 16 + l15];
#pragma unroll
    for (int mf = 0; mf < 2; ++mf) {
#pragma unroll
        for (int r = 0; r < 4; ++r) {
            int row = m0 + mf * 16 + quad * 4 + r;
            if (row < nnodes) {
                _Float16* hp = Hh + (size_t)row * 256 + l15;
#pragma unroll
                for (int nf = 0; nf < 8; ++nf)
                    hp[nf * 16] = (_Float16)(acc[mf][nf][r] + b1v[nf]);
#pragma unroll
                for (int nf = 0; nf < 8; ++nf)
                    hp[128 + nf * 16] = (_Float16)acc[mf][8 + nf][r];
            }
        }
    }
}

// ---- edge phase: pure gather + relu-dot (byte-identical to R10) ----
// 16 lanes/edge, 4 edges per thread-slot; block = 256 thr covers 64 edges.
__global__ __launch_bounds__(256)
void edge_out(const _Float16* __restrict__ Hh, const int* __restrict__ eli,
              int E, int nnodes,
              const float* __restrict__ W2, const float* __restrict__ b2,
              float* __restrict__ out)
{
    const int t = threadIdx.x;
    const int lane = t & 63;
    const int wid = t >> 6;
    const int l15 = lane & 15;
    const int grp = lane >> 4;

    float w2v[8];
#pragma unroll
    for (int j = 0; j < 8; ++j)
        w2v[j] = W2[l15 * 8 + j];
    const float b2s = b2[0];

    const int e0 = blockIdx.x * 64 + wid * 16 + grp;

    half8v hs[4], hd[4];
    int ee[4];
#pragma unroll
    for (int i = 0; i < 4; ++i) {
        int e = e0 + i * 4;
        ee[i] = e;
        int ec = e < E ? e : E - 1;
        int s = eli[ec];
        int d = eli[E + ec];
        s = s < 0 ? 0 : (s >= nnodes ? nnodes - 1 : s);
        d = d < 0 ? 0 : (d >= nnodes ? nnodes - 1 : d);
        hs[i] = *(const half8v*)(Hh + (size_t)s * 256 + l15 * 8);
        hd[i] = *(const half8v*)(Hh + (size_t)d * 256 + 128 + l15 * 8);
    }
#pragma unroll
    for (int i = 0; i < 4; ++i) {
        float sacc = 0.f;
#pragma unroll
        for (int j = 0; j < 8; ++j) {
            float v = (float)hs[i][j] + (float)hd[i][j];
            v = v > 0.f ? v : 0.f;
            sacc = fmaf(v, w2v[j], sacc);
        }
        sacc += __shfl_xor(sacc, 1);
        sacc += __shfl_xor(sacc, 2);
        sacc += __shfl_xor(sacc, 4);
        sacc += __shfl_xor(sacc, 8);
        if (l15 == 0 && ee[i] < E)
            out[ee[i]] = sacc + b2s;
    }
}

// ---- R8 fused kernel (fp32-A variant), kept for the low-workspace fallback ----
__global__ __launch_bounds__(256, 2)
void fused_mlp_f32(const float* __restrict__ zf, const int* __restrict__ eli,
                   int E, int nnodes,
                   const unsigned short* __restrict__ BTc,
                   const float* __restrict__ b1, const float* __restrict__ W2,
                   const float* __restrict__ b2, float* __restrict__ out)
{
    __shared__ unsigned short btile[2][4][128][32];

    const int t = threadIdx.x;
    const int wid = t >> 6;
    const int lane = t & 63;
    const int l15 = lane & 15;
    const int quad = lane >> 4;
    const int m0 = blockIdx.x * 256 + wid * 64;

    unsigned offs[4], offd[4];
#pragma unroll
    for (int mf = 0; mf < 4; ++mf) {
        int e = m0 + mf * 16 + l15;
        e = e < E ? e : E - 1;
        int s = eli[e];
        int d = eli[E + e];
        s = s < 0 ? 0 : (s >= nnodes ? nnodes - 1 : s);
        d = d < 0 ? 0 : (d >= nnodes ? nnodes - 1 : d);
        offs[mf] = (unsigned)s * 1024u;
        offd[mf] = (unsigned)d * 1024u;
    }
    const char* zbb = (const char*)zf;

    const int swz = (l15 >> 1) & 3;
    const unsigned short* bbase = &btile[0][0][0][0] + l15 * 32 + (quad ^ swz) * 8;

    auto stage = [&](int kc, int buf) {
        const char* g = (const char*)BTc + kc * 32768 + wid * 1024 + lane * 16;
        char* l = (char*)&btile[buf][0][0][0] + wid * 1024 + lane * 16;
#pragma unroll
        for (int i = 0; i < 8; ++i)
            gl_lds16(g + i * 4096, l + i * 4096);
    };

    auto load_a = [&](int ks, short8* dst) {
        const unsigned* off = (ks < 8) ? offs : offd;
        const int cb = (ks & 7) * 128 + quad * 32;
#pragma unroll
        for (int mf = 0; mf < 4; ++mf) {
            const float* pf = (const float*)(zbb + (size_t)off[mf] + cb);
            float4 f0 = *(const float4*)pf;
            float4 f1 = *(const float4*)(pf + 4);
            short8 av;
            av[0] = (short)bf16rne(f0.x); av[1] = (short)bf16rne(f0.y);
            av[2] = (short)bf16rne(f0.z); av[3] = (short)bf16rne(f0.w);
            av[4] = (short)bf16rne(f1.x); av[5] = (short)bf16rne(f1.y);
            av[6] = (short)bf16rne(f1.z); av[7] = (short)bf16rne(f1.w);
            dst[mf] = av;
        }
    };

    floatx4 acc[4][8];
#pragma unroll
    for (int mf = 0; mf < 4; ++mf)
#pragma unroll
        for (int nf = 0; nf < 8; ++nf)
            acc[mf][nf] = (floatx4){0.f, 0.f, 0.f, 0.f};

    short8 A[3][4];
    stage(0, 0);
    load_a(0, A[0]);
    load_a(1, A[1]);
    __syncthreads();

#pragma unroll
    for (int kc = 0; kc < 4; ++kc) {
        if (kc < 3) stage(kc + 1, (kc + 1) & 1);

#pragma unroll
        for (int s4 = 0; s4 < 4; ++s4) {
            const int ks = kc * 4 + s4;
            if (ks + 2 < 16) load_a(ks + 2, A[(ks + 2) % 3]);

            const unsigned short* bs = bbase + (kc & 1) * 16384 + s4 * 4096;
            short8 bfr[8];
#pragma unroll
            for (int nf = 0; nf < 8; ++nf)
                bfr[nf] = *(const short8*)(bs + nf * 512);

            const short8* ac = A[ks % 3];
#pragma unroll
            for (int nf = 0; nf < 8; ++nf)
#pragma unroll
                for (int mf = 0; mf < 4; ++mf)
                    acc[mf][nf] = __builtin_amdgcn_mfma_f32_16x16x32_bf16(
                        ac[mf], bfr[nf], acc[mf][nf], 0, 0, 0);
        }

        if (kc < 3) __syncthreads();
    }

    const float b2s = b2[0];
    float b1v[8], w2v[8];
#pragma unroll
    for (int nf = 0; nf < 8; ++nf) {
        int c = nf * 16 + l15;
        b1v[nf] = b1[c];
        w2v[nf] = W2[c];
    }
#pragma unroll
    for (int mf = 0; mf < 4; ++mf) {
#pragma unroll
        for (int r = 0; r < 4; ++r) {
            float s = 0.f;
#pragma unroll
            for (int nf = 0; nf < 8; ++nf) {
                float v = acc[mf][nf][r] + b1v[nf];
                v = v > 0.f ? v : 0.f;
                s = fmaf(v, w2v[nf], s);
            }
            s += __shfl_xor(s, 1);
            s += __shfl_xor(s, 2);
            s += __shfl_xor(s, 4);
            s += __shfl_xor(s, 8);
            if (l15 == 0) {
                int e = m0 + mf * 16 + quad * 4 + r;
                if (e < E) out[e] = s + b2s;
            }
        }
    }
}

// ---- emergency fallback (tiny ws): one block per edge, fp32 vector ----
__global__ void naive_edge(const float* __restrict__ z, const int* __restrict__ eli,
                           int E, int nnodes,
                           const float* __restrict__ W1, const float* __restrict__ b1,
                           const float* __restrict__ W2, const float* __restrict__ b2,
                           float* __restrict__ out)
{
    __shared__ float red[2];
    int e = blockIdx.x;
    int j = threadIdx.x;
    int s = eli[e], d = eli[E + e];
    s = s < 0 ? 0 : (s >= nnodes ? nnodes - 1 : s);
    d = d < 0 ? 0 : (d >= nnodes ? nnodes - 1 : d);
    const float* zs = z + (long long)s * 256;
    const float* zd = z + (long long)d * 256;
    float h = b1[j];
    for (int i = 0; i < 256; ++i) h = fmaf(zs[i], W1[i * 128 + j], h);
    for (int i = 0; i < 256; ++i) h = fmaf(zd[i], W1[(256 + i) * 128 + j], h);
    h = h > 0.f ? h : 0.f;
    float v = h * W2[j];
    v += __shfl_xor(v, 1);  v += __shfl_xor(v, 2);  v += __shfl_xor(v, 4);
    v += __shfl_xor(v, 8);  v += __shfl_xor(v, 16); v += __shfl_xor(v, 32);
    if ((threadIdx.x & 63) == 0) red[threadIdx.x >> 6] = v;
    __syncthreads();
    if (threadIdx.x == 0) out[e] = red[0] + red[1] + b2[0];
}

extern "C" void kernel_launch(void* const* d_in, const int* in_sizes, int n_in,
                              void* d_out, int out_size, void* d_ws, size_t ws_size,
                              hipStream_t stream) {
    const float* z   = (const float*)d_in[0];
    const int*   eli = (const int*)d_in[1];      // int64 in reference -> int32 on device
    const float* W1  = (const float*)d_in[2];
    const float* b1  = (const float*)d_in[3];
    const float* W2  = (const float*)d_in[4];
    const float* b2  = (const float*)d_in[5];
    float*       out = (float*)d_out;

    const int E      = in_sizes[1] / 2;
    const int nnodes = in_sizes[0] / 256;

    const size_t HB   = (size_t)nnodes * 512;    // H partials fp16 [N][256]
    const size_t BT2B = 131072;                  // two-half swizzled W1 image
    const size_t BTB  = (size_t)512 * 128 * 2;   // old single image (fallback)

    const int grid_gemm = (nnodes + 127) / 128;
    const int grid_edge = (E + 63) / 64;

    if (ws_size >= HB + BT2B) {
        // primary: fp32-direct precompute GEMM (both halves/block) + gather edge phase
        _Float16*       Hh   = (_Float16*)d_ws;
        unsigned short* BTc2 = (unsigned short*)((char*)d_ws + HB);
        cvt_w1h<<<256, 256, 0, stream>>>(W1, BTc2);
        gemm_hb<<<grid_gemm, 256, 0, stream>>>(z, nnodes, BTc2, b1, Hh);
        edge_out<<<grid_edge, 256, 0, stream>>>(Hh, eli, E, nnodes, W2, b2, out);
    } else if (ws_size >= BTB) {
        unsigned short* BTc = (unsigned short*)d_ws;
        cvt_w1<<<256, 256, 0, stream>>>(W1, BTc);
        fused_mlp_f32<<<(E + 255) / 256, 256, 0, stream>>>(z, eli, E, nnodes, BTc, b1, W2, b2, out);
    } else {
        naive_edge<<<E, 128, 0, stream>>>(z, eli, E, nnodes, W1, b1, W2, b2, out);
    }
}